// Round 13
// baseline (113.174 us; speedup 1.0000x reference)
//
#include <hip/hip_runtime.h>
#include <stdint.h>
#include <math.h>

#define NROWS 8192
#define DDIM  256
#define BM    256
#define BN    128
#define GJ    8                         // column groups (grid.y)
#define COLS_PER_GROUP (NROWS / GJ)     // 1024

constexpr float INV_T  = 1.0f / 0.07f;  // fixed LSE max M0 = 1/T (|logit| <= 1/T)
constexpr float LOG2E  = 1.44269504f;
constexpr float K1     = INV_T * LOG2E; // exp2 arg: fma(acc, K1, -K1)

typedef __bf16 bf16x8 __attribute__((ext_vector_type(8)));
typedef float  f32x4  __attribute__((ext_vector_type(4)));

__device__ __forceinline__ void async_copy16(const uint16_t* g, uint16_t* l) {
    __builtin_amdgcn_global_load_lds(
        (const __attribute__((address_space(1))) uint32_t*)g,
        (__attribute__((address_space(3))) uint32_t*)l, 16, 0, 0);
}

__device__ inline uint16_t f2bf(float f) {
    uint32_t u = __float_as_uint(f);
    u += 0x7fffu + ((u >> 16) & 1u);    // RNE
    return (uint16_t)(u >> 16);
}

// Kernel 1: normalize rows to unit length (bf16 out). One wave per row.
// q-row waves ALSO compute l_pos = cos(q_i,k_i) in fp32 (validated rounds 6-12):
// LSE over [l_pos, row-with-diag-masked(-10)] == log(full unmasked row sum),
// so the main kernel needs no diagonal special-case.
__global__ __launch_bounds__(256) void norm_convert_kernel(
    const float* __restrict__ fq, const float* __restrict__ fk,
    uint16_t* __restrict__ qb, uint16_t* __restrict__ kb,
    float* __restrict__ lpT)
{
    const int wave = threadIdx.x >> 6;
    const int lane = threadIdx.x & 63;
    const int row  = blockIdx.x * 4 + wave;

    if (row < NROWS) {
        const float* qsrc = fq + (size_t)row * DDIM;
        const float* ksrc = fk + (size_t)row * DDIM;
        float4 vq = ((const float4*)qsrc)[lane];
        float4 vk = ((const float4*)ksrc)[lane];
        float ssq = vq.x*vq.x + vq.y*vq.y + vq.z*vq.z + vq.w*vq.w;
        float ssk = vk.x*vk.x + vk.y*vk.y + vk.z*vk.z + vk.w*vk.w;
        float dqk = vq.x*vk.x + vq.y*vk.y + vq.z*vk.z + vq.w*vk.w;
        #pragma unroll
        for (int m = 1; m < 64; m <<= 1) {
            ssq += __shfl_xor(ssq, m, 64);
            ssk += __shfl_xor(ssk, m, 64);
            dqk += __shfl_xor(dqk, m, 64);
        }
        float r = rsqrtf(ssq);
        ushort4 o;
        o.x = f2bf(vq.x * r); o.y = f2bf(vq.y * r); o.z = f2bf(vq.z * r); o.w = f2bf(vq.w * r);
        ((ushort4*)(qb + (size_t)row * DDIM))[lane] = o;
        if (lane == 0) {
            float denom = fmaxf(sqrtf(ssq) * sqrtf(ssk), 1e-8f);
            lpT[row] = (dqk / denom) * INV_T;
        }
    } else {
        const int r_ = row - NROWS;
        const float* src = fk + (size_t)r_ * DDIM;
        float4 v = ((const float4*)src)[lane];
        float ss = v.x*v.x + v.y*v.y + v.z*v.z + v.w*v.w;
        #pragma unroll
        for (int m = 1; m < 64; m <<= 1) ss += __shfl_xor(ss, m, 64);
        float r = rsqrtf(ss);
        ushort4 o;
        o.x = f2bf(v.x * r); o.y = f2bf(v.y * r); o.z = f2bf(v.z * r); o.w = f2bf(v.w * r);
        ((ushort4*)(kb + (size_t)r_ * DDIM))[lane] = o;
    }
}

// Kernel 2: round-9 schedule MERGED into one 256-row train per CU.
// Hypothesis (last untested): the ~600-cyc unexplained slice of the measured
// 1875-cyc dual-chunk period is per-TRAIN fixed overhead (barrier + drain +
// LDS arbitration), paid twice by the two co-resident 128-row blocks. Merge
// them: BM=256, 512 threads / 8 waves in 4x2. Each wave's per-chunk code is
// byte-identical to round 9 (64x64 tile, 4 A + 4 B ds_read_b128, 16 MFMA,
// proven conflict-free swizzles, ~88 VGPR). Per-CU totals (LDS bytes, MFMA,
// DMA) unchanged; chunk-slots per CU HALVE (one 64-chunk train vs two).
// LDS 144 KB -> 1 block/CU, 8 waves/CU (same wave population as round 9's
// 2 blocks x 4 waves). Grid 32x8 = 256 blocks = exactly 1/CU, zero tail.
// Win case: period compresses toward the ~940-cyc LDS content -> ~32 us.
// Wash case (~50 us): overhead is per-CU resource serialization -> session
// floor confirmed as a hardware/schedule-family limit.
__global__ __launch_bounds__(512, 1) void nce_main_kernel(
    const uint16_t* __restrict__ qb, const uint16_t* __restrict__ kb,
    float* __restrict__ gpl)
{
    __shared__ __align__(16) uint16_t lds_q[BM * DDIM];     // 131072 B, swizzled
    __shared__ __align__(16) uint16_t lds_k[2 * BN * 32];   // 16384 B, 2 bufs, swizzled

    const int tid    = threadIdx.x;
    const int wave   = tid >> 6;        // 0..7
    const int lane   = tid & 63;
    const int quad   = lane >> 4;
    const int lanelo = lane & 15;
    const int wr     = wave >> 1;       // 0..3 (64-row slice)
    const int wc     = wave & 1;        // 0..1 (64-col slice)
    const int rowBase      = blockIdx.x * BM;
    const int colGroupBase = blockIdx.y * COLS_PER_GROUP;

    // ---- Stage Q tile once: 8192 chunks of 16B, 16 instrs/wave, source-swizzled.
    #pragma unroll
    for (int i = 0; i < 16; ++i) {
        int S   = (wave * 16 + i) * 64 + lane;          // lds chunk id (0..8191)
        int row = S >> 5;                               // 0..255
        int ch  = (S & 31) ^ (row & 31);                // swizzle: source chunk
        async_copy16(qb + (size_t)(rowBase + row) * DDIM + ch * 8,
                     lds_q + (size_t)(wave * 16 + i) * 512);
    }

    // ---- K staging lane constants (chunk = 16B; 4 chunks per 32-col row).
    // Buffer [128 rows][32 k] = 512 chunks; 512 lanes -> 1 DMA per lane/chunk.
    int kS   = wave * 64 + lane;                        // chunk id (0..511)
    int krow = kS >> 2;                                 // 0..127
    int kch  = (lane & 3) ^ ((krow >> 1) & 3);          // proven source swizzle
    const uint16_t* kbase = kb + (size_t)(colGroupBase + krow) * DDIM + kch * 8;
    uint16_t* kl0 = lds_k + wave * 512;                 // wave-uniform dest

    // phase 0 (jt=0, kk=0) into buf 0
    async_copy16(kbase, kl0);
    __syncthreads();    // Q + first K chunk visible

    // ---- Fragment address constants (identical formulas to round 9).
    int rq[4], rq31[4];
    #pragma unroll
    for (int mt = 0; mt < 4; ++mt) {
        rq[mt]   = wr * 64 + mt * 16 + lanelo;          // 0..255
        rq31[mt] = rq[mt] & 31;
    }
    int bvoff[4];
    #pragma unroll
    for (int nt = 0; nt < 4; ++nt) {
        int rk = wc * 64 + nt * 16 + lanelo;            // 0..127
        bvoff[nt] = rk * 32 + (quad ^ ((lanelo >> 1) & 3)) * 8;  // proven read swizzle
    }

    float l_run[16];
    #pragma unroll
    for (int i = 0; i < 16; ++i) l_run[i] = 0.f;

    for (int jt = 0; jt < 8; ++jt) {
        f32x4 acc[4][4];
        #pragma unroll
        for (int mt = 0; mt < 4; ++mt)
            #pragma unroll
            for (int nt = 0; nt < 4; ++nt)
                acc[mt][nt] = (f32x4){0.f, 0.f, 0.f, 0.f};

        #pragma unroll
        for (int kk = 0; kk < 8; ++kk) {
            const int p    = (jt << 3) + kk;
            const int buf  = p & 1;
            const int nbuf = buf ^ 1;

            // Issue next chunk's load (drained only at the NEXT barrier).
            if (p < 63) {
                int np  = p + 1;
                int off = ((np >> 3) << 15) + ((np & 7) << 5);  // njt*128*256 + nkk*32
                async_copy16(kbase + off, lds_k + nbuf * 4096 + wave * 512);
            }

            // Compute on buf (byte-identical per-wave to round 9).
            bf16x8 av[4], bv[4];
            #pragma unroll
            for (int mt = 0; mt < 4; ++mt) {
                int chp = ((kk << 2) + quad) ^ rq31[mt];
                av[mt] = *(const bf16x8*)&lds_q[rq[mt] * 256 + chp * 8];
            }
            #pragma unroll
            for (int nt = 0; nt < 4; ++nt)
                bv[nt] = *(const bf16x8*)&lds_k[buf * 4096 + bvoff[nt]];
            #pragma unroll
            for (int mt = 0; mt < 4; ++mt)
                #pragma unroll
                for (int nt = 0; nt < 4; ++nt)
                    acc[mt][nt] = __builtin_amdgcn_mfma_f32_16x16x32_bf16(av[mt], bv[nt], acc[mt][nt], 0, 0, 0);

            __syncthreads();    // publish chunk p+1's writes / guard buf reuse
        }

        // Epilogue: fixed-max exp accumulate, full row, no diag special-case.
        #pragma unroll
        for (int mt = 0; mt < 4; ++mt) {
            #pragma unroll
            for (int rg = 0; rg < 4; ++rg) {
                float s = 0.f;
                #pragma unroll
                for (int nt = 0; nt < 4; ++nt)
                    s += exp2f(fmaf(acc[mt][nt][rg], K1, -K1));
                l_run[mt * 4 + rg] += s;
            }
        }
    }

    // Cross-lane reduce over the 16 lanelo lanes (same row, different cols).
    #pragma unroll
    for (int i = 0; i < 16; ++i) {
        float v = l_run[i];
        v += __shfl_xor(v, 1, 64);
        v += __shfl_xor(v, 2, 64);
        v += __shfl_xor(v, 4, 64);
        v += __shfl_xor(v, 8, 64);
        l_run[i] = v;
    }
    // All LDS reads/writes done (last barrier passed; no loads in flight).
    float* pl = (float*)lds_k;      // 512 floats scratch (2 col-halves x 256 rows)
    if (lanelo == 0) {
        #pragma unroll
        for (int mt = 0; mt < 4; ++mt)
            #pragma unroll
            for (int rg = 0; rg < 4; ++rg) {
                int lr = wr * 64 + mt * 16 + quad * 4 + rg;   // 0..255
                pl[wc * 256 + lr] = l_run[mt * 4 + rg];
            }
    }
    __syncthreads();
    if (tid < 256) {
        float L = pl[tid] + pl[256 + tid];
        gpl[(size_t)blockIdx.y * NROWS + rowBase + tid] = L;
    }
}

// Kernel 3: merge GJ partial sums; loss = M0 + log(L) - l_pos/T.
// (L already contains the diagonal = positive term; see kernel 1.)
__global__ __launch_bounds__(256) void finalize_kernel(
    const float* __restrict__ gpl, const float* __restrict__ lpT,
    float* __restrict__ out)
{
    int t = blockIdx.x * 256 + threadIdx.x;
    if (t >= NROWS) return;
    float L = 0.f;
    #pragma unroll
    for (int g = 0; g < GJ; ++g) L += gpl[g * NROWS + t];
    out[t] = INV_T + __logf(L) - lpT[t];
}

extern "C" void kernel_launch(void* const* d_in, const int* in_sizes, int n_in,
                              void* d_out, int out_size, void* d_ws, size_t ws_size,
                              hipStream_t stream) {
    const float* fq = (const float*)d_in[0];
    const float* fk = (const float*)d_in[1];
    char* ws = (char*)d_ws;
    // layout: qb 4MB | kb 4MB | lpT 32KB | gpl 256KB
    uint16_t* qb  = (uint16_t*)(ws);
    uint16_t* kb  = (uint16_t*)(ws + 4194304);
    float*    lpT = (float*)(ws + 8388608);
    float*    gpl = (float*)(ws + 8421376);

    norm_convert_kernel<<<(2 * NROWS) / 4, 256, 0, stream>>>(fq, fk, qb, kb, lpT);
    dim3 grid(NROWS / BM, GJ);
    nce_main_kernel<<<grid, 512, 0, stream>>>(qb, kb, gpl);
    finalize_kernel<<<NROWS / 256, 256, 0, stream>>>(gpl, lpT, (float*)d_out);
}

// Round 14
// 110.754 us; speedup vs baseline: 1.0218x; 1.0218x over previous
//
#include <hip/hip_runtime.h>
#include <stdint.h>
#include <math.h>

#define NROWS 8192
#define DDIM  256
#define BM    128
#define BN    128
#define GJ    8                         // column groups (grid.y)
#define COLS_PER_GROUP (NROWS / GJ)     // 1024

constexpr float INV_T  = 1.0f / 0.07f;  // fixed LSE max M0 = 1/T (|logit| <= 1/T)
constexpr float LOG2E  = 1.44269504f;
constexpr float K1     = INV_T * LOG2E; // exp2 arg: fma(acc, K1, -K1)

typedef __bf16 bf16x8 __attribute__((ext_vector_type(8)));
typedef float  f32x4  __attribute__((ext_vector_type(4)));

__device__ __forceinline__ void async_copy16(const uint16_t* g, uint16_t* l) {
    __builtin_amdgcn_global_load_lds(
        (const __attribute__((address_space(1))) uint32_t*)g,
        (__attribute__((address_space(3))) uint32_t*)l, 16, 0, 0);
}

__device__ inline uint16_t f2bf(float f) {
    uint32_t u = __float_as_uint(f);
    u += 0x7fffu + ((u >> 16) & 1u);    // RNE
    return (uint16_t)(u >> 16);
}

// Kernel 1: normalize rows to unit length (bf16 out). One wave per row.
// q-row waves ALSO compute l_pos = cos(q_i,k_i) in fp32 (validated rounds 6-13):
// LSE over [l_pos, row-with-diag-masked(-10)] == log(full unmasked row sum),
// so the main kernel needs no diagonal special-case.
__global__ __launch_bounds__(256) void norm_convert_kernel(
    const float* __restrict__ fq, const float* __restrict__ fk,
    uint16_t* __restrict__ qb, uint16_t* __restrict__ kb,
    float* __restrict__ lpT)
{
    const int wave = threadIdx.x >> 6;
    const int lane = threadIdx.x & 63;
    const int row  = blockIdx.x * 4 + wave;

    if (row < NROWS) {
        const float* qsrc = fq + (size_t)row * DDIM;
        const float* ksrc = fk + (size_t)row * DDIM;
        float4 vq = ((const float4*)qsrc)[lane];
        float4 vk = ((const float4*)ksrc)[lane];
        float ssq = vq.x*vq.x + vq.y*vq.y + vq.z*vq.z + vq.w*vq.w;
        float ssk = vk.x*vk.x + vk.y*vk.y + vk.z*vk.z + vk.w*vk.w;
        float dqk = vq.x*vk.x + vq.y*vk.y + vq.z*vk.z + vq.w*vk.w;
        #pragma unroll
        for (int m = 1; m < 64; m <<= 1) {
            ssq += __shfl_xor(ssq, m, 64);
            ssk += __shfl_xor(ssk, m, 64);
            dqk += __shfl_xor(dqk, m, 64);
        }
        float r = rsqrtf(ssq);
        ushort4 o;
        o.x = f2bf(vq.x * r); o.y = f2bf(vq.y * r); o.z = f2bf(vq.z * r); o.w = f2bf(vq.w * r);
        ((ushort4*)(qb + (size_t)row * DDIM))[lane] = o;
        if (lane == 0) {
            float denom = fmaxf(sqrtf(ssq) * sqrtf(ssk), 1e-8f);
            lpT[row] = (dqk / denom) * INV_T;
        }
    } else {
        const int r_ = row - NROWS;
        const float* src = fk + (size_t)r_ * DDIM;
        float4 v = ((const float4*)src)[lane];
        float ss = v.x*v.x + v.y*v.y + v.z*v.z + v.w*v.w;
        #pragma unroll
        for (int m = 1; m < 64; m <<= 1) ss += __shfl_xor(ss, m, 64);
        float r = rsqrtf(ss);
        ushort4 o;
        o.x = f2bf(v.x * r); o.y = f2bf(v.y * r); o.z = f2bf(v.z * r); o.w = f2bf(v.w * r);
        ((ushort4*)(kb + (size_t)r_ * DDIM))[lane] = o;
    }
}

// Kernel 2: barrier-free (round-8 proven sync) x read-minimal 128x64 wave
// tiles x dense MFMA. Round-13 established the floor mechanism: the barrier
// phase-locks all waves, so per-chunk time = LDS content + MFMA content
// (sum, not max). Round 8 proved the barrier-free wave-private pattern is
// correct but its 128x32 tiles doubled A-reads. This geometry fixes that:
// block = 2 waves x 64 thr; each wave owns 128 rows x 64 cols -> per chunk
// 8 A-reads + 4 B-reads (12 KB) + 32 back-to-back MFMA, and stages its OWN
// 64-col B slice (4 KB = 4 DMA, zero duplication -- waves partition cols).
// Per work unit: 32 KB LDS traffic (vs R9 40, R8 48); per-wave MFMA:LDS
// ratio 4:1 -- the wave's own MFMA train hides LDS/DMA latency instead of
// occupancy. DMA prefetch distance 2 (~1700 cyc slack > 900 HBM latency).
// 80 KB LDS -> 2 blocks/CU = 4 waves (1/SIMD, all 4 SIMDs fed).
// All swizzle/read formulas are the session's proven conflict-free ones.
__global__ __launch_bounds__(128, 1) void nce_main_kernel(
    const uint16_t* __restrict__ qb, const uint16_t* __restrict__ kb,
    float* __restrict__ gpl)
{
    __shared__ __align__(16) uint16_t lds_q[BM * DDIM];   // 65536 B, swizzled
    __shared__ __align__(16) uint16_t lds_k[2 * 2 * 2048];// 2 waves x 2 bufs x 4KB = 16KB

    const int tid    = threadIdx.x;
    const int wave   = tid >> 6;        // 0..1 = column half
    const int lane   = tid & 63;
    const int quad   = lane >> 4;
    const int lanelo = lane & 15;
    const int rowBase      = blockIdx.x * BM;
    const int colGroupBase = blockIdx.y * COLS_PER_GROUP;

    // ---- Stage Q tile once: 4096 chunks of 16B, 32 instrs/wave, source-swizzled.
    #pragma unroll
    for (int i = 0; i < 32; ++i) {
        int S   = (wave * 32 + i) * 64 + lane;          // lds chunk id (0..4095)
        int row = S >> 5;
        int ch  = (S & 31) ^ (row & 31);                // proven swizzle
        async_copy16(qb + (size_t)(rowBase + row) * DDIM + ch * 8,
                     lds_q + (size_t)(wave * 32 + i) * 512);
    }

    // ---- Wave-private B staging. Slice buf = [64 rows][32 k] bf16 = 4 KB =
    // 256 chunks of 16B; 4 DMA instr/chunk (j=0..3 cover 16 rows each).
    // Chunk S = j*64+lane -> row r = j*16+(lane>>2), pos = lane&3; source
    // chunk = pos ^ ((r>>1)&3) = (lane&3)^((lane>>3)&3), j-independent.
    const int c0 = (lane & 3) ^ ((lane >> 3) & 3);
    const uint16_t* kb_r =
        kb + (size_t)(colGroupBase + wave * 64 + (lane >> 2)) * DDIM + c0 * 8;
    uint16_t* kw = lds_k + wave * 4096;                 // uint16; 2 bufs x 2048

    // chunks 0 (buf0) and 1 (buf1)
    #pragma unroll
    for (int b = 0; b < 2; ++b)
        #pragma unroll
        for (int j = 0; j < 4; ++j)
            async_copy16(kb_r + j * 4096 + b * 32, kw + b * 2048 + j * 512);

    __syncthreads();    // Q visible to both waves; all prologue DMAs drained.

    // ---- B fragment offsets (proven conflict-free): row rs = nt*16+lanelo,
    // k-chunk quad stored at quad ^ ((rs>>1)&3) = quad ^ ((lanelo>>1)&3).
    int bvoff[4];
    #pragma unroll
    for (int nt = 0; nt < 4; ++nt)
        bvoff[nt] = (nt * 16 + lanelo) * 32 + (quad ^ ((lanelo >> 1) & 3)) * 8;

    float l_run[32];
    #pragma unroll
    for (int i = 0; i < 32; ++i) l_run[i] = 0.f;

    for (int jt = 0; jt < 8; ++jt) {
        f32x4 acc[8][4];
        #pragma unroll
        for (int mt = 0; mt < 8; ++mt)
            #pragma unroll
            for (int nt = 0; nt < 4; ++nt)
                acc[mt][nt] = (f32x4){0.f, 0.f, 0.f, 0.f};

        #pragma unroll
        for (int kk = 0; kk < 8; ++kk) {
            const int p = (jt << 3) + kk;

            // Wait own chunk p (4 DMA); leaves chunk p+1's 4 in flight.
            // Per-wave counter -- no cross-wave coupling.
            asm volatile("s_waitcnt vmcnt(4)" ::: "memory");

            // ds_read fragments: 8 A (whole 128-row Q, proven pattern) + 4 B.
            bf16x8 av[8], bv[4];
            #pragma unroll
            for (int mt = 0; mt < 8; ++mt) {
                int rq  = mt * 16 + lanelo;
                int chp = ((kk << 2) + quad) ^ (lanelo + ((mt & 1) << 4));
                av[mt] = *(const bf16x8*)&lds_q[rq * 256 + chp * 8];
            }
            const int bufo = (p & 1) << 11;             // 2048 uint16 per buf
            #pragma unroll
            for (int nt = 0; nt < 4; ++nt)
                bv[nt] = *(const bf16x8*)&lds_k[wave * 4096 + bufo + bvoff[nt]];

            // Retire reads, then overwrite buf p&1 with chunk p+2
            // (~1.7 chunk-periods of slack before its vmcnt wait).
            asm volatile("s_waitcnt lgkmcnt(0)" ::: "memory");
            {
                const int np  = (p + 2) & 63;           // tail wraps: never read
                const int off = ((np >> 3) << 15) + ((np & 7) << 5);
                #pragma unroll
                for (int j = 0; j < 4; ++j)
                    async_copy16(kb_r + j * 4096 + off, kw + bufo + j * 512);
            }
            __builtin_amdgcn_sched_barrier(0);          // pin MFMAs below wait+DMA

            // 32 back-to-back MFMA (independent accs -> fully pipelined).
            #pragma unroll
            for (int mt = 0; mt < 8; ++mt)
                #pragma unroll
                for (int nt = 0; nt < 4; ++nt)
                    acc[mt][nt] = __builtin_amdgcn_mfma_f32_16x16x32_bf16(
                        av[mt], bv[nt], acc[mt][nt], 0, 0, 0);
        }

        // Epilogue: fixed-max exp accumulate, full row, no diag special-case.
        #pragma unroll
        for (int mt = 0; mt < 8; ++mt) {
            #pragma unroll
            for (int rg = 0; rg < 4; ++rg) {
                float s = 0.f;
                #pragma unroll
                for (int nt = 0; nt < 4; ++nt)
                    s += exp2f(fmaf(acc[mt][nt][rg], K1, -K1));
                l_run[mt * 4 + rg] += s;
            }
        }
    }

    // Cross-lane reduce over the 16 lanelo lanes (same row, different cols).
    #pragma unroll
    for (int i = 0; i < 32; ++i) {
        float v = l_run[i];
        v += __shfl_xor(v, 1, 64);
        v += __shfl_xor(v, 2, 64);
        v += __shfl_xor(v, 4, 64);
        v += __shfl_xor(v, 8, 64);
        l_run[i] = v;
    }

    // Drain wrap DMAs + resync both waves before reusing lds_k as scratch.
    __syncthreads();

    float* pl = (float*)lds_k;      // 2 waves x 128 rows = 256 floats
    if (lanelo == 0) {
        #pragma unroll
        for (int mt = 0; mt < 8; ++mt)
            #pragma unroll
            for (int rg = 0; rg < 4; ++rg)
                pl[wave * 128 + mt * 16 + quad * 4 + rg] = l_run[mt * 4 + rg];
    }
    __syncthreads();
    if (tid < 128) {
        float L = pl[tid] + pl[128 + tid];
        gpl[(size_t)blockIdx.y * NROWS + rowBase + tid] = L;
    }
}

// Kernel 3: merge GJ partial sums; loss = M0 + log(L) - l_pos/T.
// (L already contains the diagonal = positive term; see kernel 1.)
__global__ __launch_bounds__(256) void finalize_kernel(
    const float* __restrict__ gpl, const float* __restrict__ lpT,
    float* __restrict__ out)
{
    int t = blockIdx.x * 256 + threadIdx.x;
    if (t >= NROWS) return;
    float L = 0.f;
    #pragma unroll
    for (int g = 0; g < GJ; ++g) L += gpl[g * NROWS + t];
    out[t] = INV_T + __logf(L) - lpT[t];
}

extern "C" void kernel_launch(void* const* d_in, const int* in_sizes, int n_in,
                              void* d_out, int out_size, void* d_ws, size_t ws_size,
                              hipStream_t stream) {
    const float* fq = (const float*)d_in[0];
    const float* fk = (const float*)d_in[1];
    char* ws = (char*)d_ws;
    // layout: qb 4MB | kb 4MB | lpT 32KB | gpl 256KB
    uint16_t* qb  = (uint16_t*)(ws);
    uint16_t* kb  = (uint16_t*)(ws + 4194304);
    float*    lpT = (float*)(ws + 8388608);
    float*    gpl = (float*)(ws + 8421376);

    norm_convert_kernel<<<(2 * NROWS) / 4, 256, 0, stream>>>(fq, fk, qb, kb, lpT);
    dim3 grid(NROWS / BM, GJ);
    nce_main_kernel<<<grid, 128, 0, stream>>>(qb, kb, gpl);
    finalize_kernel<<<NROWS / 256, 256, 0, stream>>>(gpl, lpT, (float*)d_out);
}